// Round 8
// baseline (260.199 us; speedup 1.0000x reference)
//
#include <hip/hip_runtime.h>

typedef unsigned int u32;
typedef unsigned short u16;
typedef unsigned long long u64;

#define NTOK 4096
#define DDIM 512
#define NEXP 8
#define HDIM 1024

typedef __attribute__((ext_vector_type(8))) __bf16 bf16x8;
typedef __attribute__((ext_vector_type(4))) float f32x4;

__device__ __forceinline__ float b2f(u16 u) {
    union { u32 i; float f; } v; v.i = ((u32)u) << 16; return v.f;
}
__device__ __forceinline__ u16 f2b(float f) {
    u32 x = __builtin_bit_cast(u32, f);
    x += 0x7fffu + ((x >> 16) & 1u);
    return (u16)(x >> 16);
}

// MODE 0 = tensors are bf16 in memory; MODE 1 = tensors are f32 in memory.
template<int MODE>
__device__ __forceinline__ float ldf(const void* p, size_t i) {
    return MODE ? ((const float*)p)[i] : b2f(((const u16*)p)[i]);
}

template<int MODE>
__device__ __forceinline__ void load16(const void* base, size_t elem, uint4& lo, uint4& hi) {
    if (MODE == 0) {
        const uint4* p = (const uint4*)((const u16*)base + elem);
        lo = p[0]; hi = p[1];
    } else {
        const float4* p = (const float4*)((const float*)base + elem);
        const float4 a = p[0], b = p[1], c = p[2], d = p[3];
        union { u16 t[16]; uint4 v[2]; } u;
        u.t[0] = f2b(a.x); u.t[1] = f2b(a.y); u.t[2]  = f2b(a.z); u.t[3]  = f2b(a.w);
        u.t[4] = f2b(b.x); u.t[5] = f2b(b.y); u.t[6]  = f2b(b.z); u.t[7]  = f2b(b.w);
        u.t[8] = f2b(c.x); u.t[9] = f2b(c.y); u.t[10] = f2b(c.z); u.t[11] = f2b(c.w);
        u.t[12] = f2b(d.x); u.t[13] = f2b(d.y); u.t[14] = f2b(d.z); u.t[15] = f2b(d.w);
        lo = u.v[0]; hi = u.v[1];
    }
}

// ---------------- K0: detect dtype + zero expert counts ----------------
__global__ void detect_kernel(const u16* __restrict__ x, u32* __restrict__ flag,
                              u32* __restrict__ counts) {
    const int lane = threadIdx.x & 63;
    const u16 v = x[lane * 2];
    const int ex = (v >> 7) & 0xFF;
    const bool ok = (ex >= 97 && ex <= 140);   // |val| in [2^-30, 2^14]
    const u64 m = __ballot(ok);
    if (threadIdx.x == 0) *flag = (__popcll(m) >= 32) ? 0u : 1u;
    if (threadIdx.x < NEXP) counts[threadIdx.x] = 0;
}

// ---------------- K1: router (64 tokens/block, LDS-aggregated atomics) ----------------
template<int MODE>
__global__ __launch_bounds__(256) void router_kernel(
    const u32* __restrict__ flag,
    const void* __restrict__ x, const void* __restrict__ rw, const void* __restrict__ rb,
    u32* __restrict__ counts, u16* __restrict__ list,
    u32* __restrict__ tok_e, u32* __restrict__ tok_pos, float* __restrict__ tok_w)
{
    if (*flag != (u32)MODE) return;
    __shared__ u32 bcount[NEXP];
    __shared__ u32 bbase[NEXP];
    __shared__ u32 srank[128];
    __shared__ u16 sexp[128];

    const int tid = threadIdx.x;
    const int lane = tid & 63;
    const int wave = tid >> 6;
    if (tid < NEXP) bcount[tid] = 0;

    float wreg[NEXP][8];
#pragma unroll
    for (int e = 0; e < NEXP; e++) {
        if (MODE == 0) {
            const uint4 wv = ((const uint4*)((const u16*)rw + e * DDIM))[lane];
            const u16* wp = (const u16*)&wv;
#pragma unroll
            for (int i = 0; i < 8; i++) wreg[e][i] = b2f(wp[i]);
        } else {
            const float4* p = (const float4*)((const float*)rw + e * DDIM + lane * 8);
            const float4 a = p[0], b = p[1];
            wreg[e][0] = a.x; wreg[e][1] = a.y; wreg[e][2] = a.z; wreg[e][3] = a.w;
            wreg[e][4] = b.x; wreg[e][5] = b.y; wreg[e][6] = b.z; wreg[e][7] = b.w;
        }
    }
    float bias[NEXP];
#pragma unroll
    for (int e = 0; e < NEXP; e++) bias[e] = ldf<MODE>(rb, e);

    __syncthreads();

    const int t0 = blockIdx.x * 64;
    for (int tk = 0; tk < 16; tk++) {
        const int lt = wave * 16 + tk;
        const int t = t0 + lt;
        float xf[8];
        if (MODE == 0) {
            const uint4 xv = ((const uint4*)((const u16*)x + (size_t)t * DDIM))[lane];
            const u16* xs = (const u16*)&xv;
#pragma unroll
            for (int i = 0; i < 8; i++) xf[i] = b2f(xs[i]);
        } else {
            const float4* p = (const float4*)((const float*)x + (size_t)t * DDIM + lane * 8);
            const float4 a = p[0], b = p[1];
            xf[0] = a.x; xf[1] = a.y; xf[2] = a.z; xf[3] = a.w;
            xf[4] = b.x; xf[5] = b.y; xf[6] = b.z; xf[7] = b.w;
        }
        float acc[NEXP];
#pragma unroll
        for (int e = 0; e < NEXP; e++) {
            float s = 0.f;
#pragma unroll
            for (int i = 0; i < 8; i++) s += xf[i] * wreg[e][i];
            acc[e] = s;
        }
#pragma unroll
        for (int off = 32; off > 0; off >>= 1) {
#pragma unroll
            for (int e = 0; e < NEXP; e++) acc[e] += __shfl_xor(acc[e], off, 64);
        }
        if (lane == 0) {
#pragma unroll
            for (int e = 0; e < NEXP; e++) acc[e] += bias[e];
            int e0 = 0;
#pragma unroll
            for (int e = 1; e < NEXP; e++) if (acc[e] > acc[e0]) e0 = e;
            int e1 = -1;
#pragma unroll
            for (int e = 0; e < NEXP; e++) {
                if (e == e0) continue;
                if (e1 < 0 || acc[e] > acc[e1]) e1 = e;
            }
            const float w1v = 1.f / (1.f + __expf(acc[e0] - acc[e1]));
            tok_e[t * 2] = (u32)e0;      tok_w[t * 2] = 1.f - w1v;
            tok_e[t * 2 + 1] = (u32)e1;  tok_w[t * 2 + 1] = w1v;
            sexp[lt * 2] = (u16)e0;
            sexp[lt * 2 + 1] = (u16)e1;
            srank[lt * 2]     = atomicAdd(&bcount[e0], 1u);
            srank[lt * 2 + 1] = atomicAdd(&bcount[e1], 1u);
        }
    }
    __syncthreads();
    if (tid < NEXP) bbase[tid] = atomicAdd(&counts[tid], bcount[tid]);
    __syncthreads();
    if (tid < 128) {
        const int s = tid;
        const int lt = s >> 1;
        const int t = t0 + lt;
        const u32 e = (u32)sexp[s];
        const u32 pos = bbase[e] + srank[s];
        list[e * NTOK + pos] = (u16)t;
        tok_pos[t * 2 + (s & 1)] = pos;
    }
}

// ---------------- K2: exclusive prefix over 8 counts ----------------
__global__ void prefix_kernel(const u32* __restrict__ counts, u32* __restrict__ offsets) {
    if (threadIdx.x == 0) {
        u32 o = 0;
        for (int e = 0; e < NEXP; e++) { offsets[e] = o; o += counts[e]; }
    }
}

// ---------------- K3: gathered fc1 + SwiGLU, 128x64 tile, prefetched ----------------
// 1-D grid with multiplicative scramble: active (row0<cnt) logical blocks are
// ~25% of the grid and cluster in [512e, 512e+128) -> without the scramble
// they land on half the CUs (round-7 measured occupancy 22%).
template<int MODE>
__global__ __launch_bounds__(256, 3) void fc1_swiglu_kernel(
    const u32* __restrict__ flag,
    const void* __restrict__ x, const void* __restrict__ fc1_w, const void* __restrict__ fc1_b,
    const u32* __restrict__ counts, const u32* __restrict__ offsets,
    const u16* __restrict__ list, u16* __restrict__ a_packed)
{
    if (*flag != (u32)MODE) return;
    const u32 bswz = (blockIdx.x * 1739u) & 4095u;   // odd mult -> bijection mod 4096
    const int e  = (int)(bswz >> 9);         // expert   0..7
    const int yb = (int)((bswz >> 4) & 31);  // row tile 0..31
    const int nb = (int)(bswz & 15);         // col tile 0..15
    const int cnt = (int)counts[e];
    const int row0 = yb * 128;
    if (row0 >= cnt) return;
    const int n0 = nb * 64;

    __shared__ u16 As[128 * 64], B1s[64 * 64], B2s[64 * 64];

    const int tid = threadIdx.x;
    const int lr = tid >> 2;
    const int lcc = tid & 3;
    const int lc = lcc * 16;

    int ar0 = row0 + lr;       if (ar0 >= cnt) ar0 = cnt - 1;
    int ar1 = row0 + 64 + lr;  if (ar1 >= cnt) ar1 = cnt - 1;
    const int tok0 = min((int)list[e * NTOK + ar0], NTOK - 1);
    const int tok1 = min((int)list[e * NTOK + ar1], NTOK - 1);
    const size_t a_base0 = (size_t)tok0 * DDIM;
    const size_t a_base1 = (size_t)tok1 * DDIM;
    const size_t b1_base = ((size_t)e * 2 * HDIM + (size_t)(n0 + lr)) * DDIM;
    const size_t b2_base = ((size_t)e * 2 * HDIM + (size_t)(n0 + HDIM + lr)) * DDIM;

    const int sw = lr & 7;
    const int c0 = lcc * 2;
    u16* as0a = &As[lr * 64 + ((c0 ^ sw) << 3)];
    u16* as0b = &As[lr * 64 + (((c0 + 1) ^ sw) << 3)];
    u16* as1a = &As[(lr + 64) * 64 + ((c0 ^ sw) << 3)];
    u16* as1b = &As[(lr + 64) * 64 + (((c0 + 1) ^ sw) << 3)];
    u16* b1a  = &B1s[lr * 64 + ((c0 ^ sw) << 3)];
    u16* b1b  = &B1s[lr * 64 + (((c0 + 1) ^ sw) << 3)];
    u16* b2a  = &B2s[lr * 64 + ((c0 ^ sw) << 3)];
    u16* b2b  = &B2s[lr * 64 + (((c0 + 1) ^ sw) << 3)];

    const int wave = tid >> 6, lane = tid & 63;
    const int mrow0 = (wave >> 1) * 64;
    const int ncol0 = (wave & 1) * 32;
    const int mm = lane & 15;
    const int qb = lane >> 4;
    const int msw = mm & 7;

    f32x4 acc1[4][2], acc2[4][2];
#pragma unroll
    for (int mt = 0; mt < 4; mt++)
#pragma unroll
        for (int nt = 0; nt < 2; nt++) {
            acc1[mt][nt] = f32x4{0, 0, 0, 0};
            acc2[mt][nt] = f32x4{0, 0, 0, 0};
        }

    uint4 A0l, A0h, A1l, A1h, B1l, B1h, B2l, B2h;
    load16<MODE>(x,     a_base0 + lc, A0l, A0h);
    load16<MODE>(x,     a_base1 + lc, A1l, A1h);
    load16<MODE>(fc1_w, b1_base + lc, B1l, B1h);
    load16<MODE>(fc1_w, b2_base + lc, B2l, B2h);

    for (int k0 = 0; k0 < DDIM; k0 += 64) {
        __syncthreads();
        *(uint4*)as0a = A0l; *(uint4*)as0b = A0h;
        *(uint4*)as1a = A1l; *(uint4*)as1b = A1h;
        *(uint4*)b1a  = B1l; *(uint4*)b1b  = B1h;
        *(uint4*)b2a  = B2l; *(uint4*)b2b  = B2h;
        __syncthreads();
        if (k0 + 64 < DDIM) {
            load16<MODE>(x,     a_base0 + k0 + 64 + lc, A0l, A0h);
            load16<MODE>(x,     a_base1 + k0 + 64 + lc, A1l, A1h);
            load16<MODE>(fc1_w, b1_base + k0 + 64 + lc, B1l, B1h);
            load16<MODE>(fc1_w, b2_base + k0 + 64 + lc, B2l, B2h);
        }
#pragma unroll
        for (int kk = 0; kk < 2; kk++) {
            const int g = kk * 4 + qb;
            bf16x8 af[4];
#pragma unroll
            for (int mt = 0; mt < 4; mt++)
                af[mt] = *(const bf16x8*)(&As[(mrow0 + mt * 16 + mm) * 64 + ((g ^ msw) << 3)]);
#pragma unroll
            for (int nt = 0; nt < 2; nt++) {
                const bf16x8 b1f = *(const bf16x8*)(&B1s[(ncol0 + nt * 16 + mm) * 64 + ((g ^ msw) << 3)]);
                const bf16x8 b2f = *(const bf16x8*)(&B2s[(ncol0 + nt * 16 + mm) * 64 + ((g ^ msw) << 3)]);
#pragma unroll
                for (int mt = 0; mt < 4; mt++) {
                    acc1[mt][nt] = __builtin_amdgcn_mfma_f32_16x16x32_bf16(af[mt], b1f, acc1[mt][nt], 0, 0, 0);
                    acc2[mt][nt] = __builtin_amdgcn_mfma_f32_16x16x32_bf16(af[mt], b2f, acc2[mt][nt], 0, 0, 0);
                }
            }
        }
    }

    const u32 obase = offsets[e];
    const int rbv = qb * 4;
#pragma unroll
    for (int nt = 0; nt < 2; nt++) {
        const int n = n0 + ncol0 + nt * 16 + mm;
        const float bb1 = ldf<MODE>(fc1_b, (size_t)e * 2 * HDIM + n);
        const float bb2 = ldf<MODE>(fc1_b, (size_t)e * 2 * HDIM + HDIM + n);
#pragma unroll
        for (int mt = 0; mt < 4; mt++) {
#pragma unroll
            for (int r = 0; r < 4; r++) {
                const int gr = row0 + mrow0 + mt * 16 + rbv + r;
                if (gr < cnt) {
                    const float h1 = acc1[mt][nt][r] + bb1;
                    const float h2 = acc2[mt][nt][r] + bb2;
                    const float av = h1 / (1.f + __expf(-h1)) * h2;
                    a_packed[(size_t)(obase + (u32)gr) * HDIM + n] = f2b(av);
                }
            }
        }
    }
}

// ---------------- K4: fc2, 128x64 tile, prefetched, scrambled grid ----------------
template<int MODE>
__global__ __launch_bounds__(256, 3) void fc2_kernel(
    const u32* __restrict__ flag,
    const u16* __restrict__ a_packed, const void* __restrict__ fc2_w, const void* __restrict__ fc2_b,
    const u32* __restrict__ counts, const u32* __restrict__ offsets,
    u16* __restrict__ y_packed)
{
    if (*flag != (u32)MODE) return;
    const u32 bswz = (blockIdx.x * 1739u) & 2047u;   // odd mult -> bijection mod 2048
    const int e  = (int)(bswz >> 8);         // expert   0..7
    const int yb = (int)((bswz >> 3) & 31);  // row tile 0..31
    const int db = (int)(bswz & 7);          // col tile 0..7
    const int cnt = (int)counts[e];
    const int row0 = yb * 128;
    if (row0 >= cnt) return;
    const int d0 = db * 64;

    __shared__ u16 As[128 * 64], Bs[64 * 64];

    const int tid = threadIdx.x;
    const int lr = tid >> 2;
    const int lcc = tid & 3;
    const int lc = lcc * 16;
    const u32 obase = offsets[e];

    int ar0 = row0 + lr;       if (ar0 >= cnt) ar0 = cnt - 1;
    int ar1 = row0 + 64 + lr;  if (ar1 >= cnt) ar1 = cnt - 1;
    const size_t a_base0 = (size_t)(obase + (u32)ar0) * HDIM;
    const size_t a_base1 = (size_t)(obase + (u32)ar1) * HDIM;
    const size_t b_base  = ((size_t)e * DDIM + (size_t)(d0 + lr)) * HDIM;

    const int sw = lr & 7;
    const int c0 = lcc * 2;
    u16* as0a = &As[lr * 64 + ((c0 ^ sw) << 3)];
    u16* as0b = &As[lr * 64 + (((c0 + 1) ^ sw) << 3)];
    u16* as1a = &As[(lr + 64) * 64 + ((c0 ^ sw) << 3)];
    u16* as1b = &As[(lr + 64) * 64 + (((c0 + 1) ^ sw) << 3)];
    u16* bsa  = &Bs[lr * 64 + ((c0 ^ sw) << 3)];
    u16* bsb  = &Bs[lr * 64 + (((c0 + 1) ^ sw) << 3)];

    const int wave = tid >> 6, lane = tid & 63;
    const int mrow0 = (wave >> 1) * 64;
    const int ncol0 = (wave & 1) * 32;
    const int mm = lane & 15;
    const int qb = lane >> 4;
    const int msw = mm & 7;

    f32x4 acc[4][2];
#pragma unroll
    for (int mt = 0; mt < 4; mt++)
#pragma unroll
        for (int nt = 0; nt < 2; nt++) acc[mt][nt] = f32x4{0, 0, 0, 0};

    uint4 A0l, A0h, A1l, A1h, Bl, Bh;
    load16<0>(a_packed, a_base0 + lc, A0l, A0h);
    load16<0>(a_packed, a_base1 + lc, A1l, A1h);
    load16<MODE>(fc2_w, b_base + lc, Bl, Bh);

    for (int k0 = 0; k0 < HDIM; k0 += 64) {
        __syncthreads();
        *(uint4*)as0a = A0l; *(uint4*)as0b = A0h;
        *(uint4*)as1a = A1l; *(uint4*)as1b = A1h;
        *(uint4*)bsa  = Bl;  *(uint4*)bsb  = Bh;
        __syncthreads();
        if (k0 + 64 < HDIM) {
            load16<0>(a_packed, a_base0 + k0 + 64 + lc, A0l, A0h);
            load16<0>(a_packed, a_base1 + k0 + 64 + lc, A1l, A1h);
            load16<MODE>(fc2_w, b_base + k0 + 64 + lc, Bl, Bh);
        }
#pragma unroll
        for (int kk = 0; kk < 2; kk++) {
            const int g = kk * 4 + qb;
            bf16x8 af[4];
#pragma unroll
            for (int mt = 0; mt < 4; mt++)
                af[mt] = *(const bf16x8*)(&As[(mrow0 + mt * 16 + mm) * 64 + ((g ^ msw) << 3)]);
#pragma unroll
            for (int nt = 0; nt < 2; nt++) {
                const bf16x8 bfv = *(const bf16x8*)(&Bs[(ncol0 + nt * 16 + mm) * 64 + ((g ^ msw) << 3)]);
#pragma unroll
                for (int mt = 0; mt < 4; mt++)
                    acc[mt][nt] = __builtin_amdgcn_mfma_f32_16x16x32_bf16(af[mt], bfv, acc[mt][nt], 0, 0, 0);
            }
        }
    }

    const int rbv = qb * 4;
#pragma unroll
    for (int nt = 0; nt < 2; nt++) {
        const int n = d0 + ncol0 + nt * 16 + mm;
        const float bb = ldf<MODE>(fc2_b, (size_t)e * DDIM + n);
#pragma unroll
        for (int mt = 0; mt < 4; mt++) {
#pragma unroll
            for (int r = 0; r < 4; r++) {
                const int gr = row0 + mrow0 + mt * 16 + rbv + r;
                if (gr < cnt) {
                    y_packed[(size_t)(obase + (u32)gr) * DDIM + n] = f2b(acc[mt][nt][r] + bb);
                }
            }
        }
    }
}

// ---------------- K5: weighted combine ----------------
template<int MODE>
__global__ __launch_bounds__(256) void combine_kernel(
    const u32* __restrict__ flag,
    const u16* __restrict__ y_packed, const u32* __restrict__ offsets,
    const u32* __restrict__ tok_e, const u32* __restrict__ tok_pos,
    const float* __restrict__ tok_w, void* __restrict__ out)
{
    if (*flag != (u32)MODE) return;
    const int t = blockIdx.x;
    const u32 e0 = tok_e[t * 2] & 7u, e1 = tok_e[t * 2 + 1] & 7u;
    const u32 p0 = min(offsets[e0] + tok_pos[t * 2], (u32)(2 * NTOK - 1));
    const u32 p1 = min(offsets[e1] + tok_pos[t * 2 + 1], (u32)(2 * NTOK - 1));
    const float w0 = tok_w[t * 2], w1 = tok_w[t * 2 + 1];
    const u16* y0 = y_packed + (size_t)p0 * DDIM;
    const u16* y1 = y_packed + (size_t)p1 * DDIM;
    for (int c = threadIdx.x; c < DDIM; c += 256) {
        const float v = w0 * b2f(y0[c]) + w1 * b2f(y1[c]);
        if (MODE == 0) ((u16*)out)[(size_t)t * DDIM + c] = f2b(v);
        else           ((float*)out)[(size_t)t * DDIM + c] = v;
    }
}

extern "C" void kernel_launch(void* const* d_in, const int* in_sizes, int n_in,
                              void* d_out, int out_size, void* d_ws, size_t ws_size,
                              hipStream_t stream)
{
    const void* x     = d_in[0];
    const void* rw    = d_in[1];
    const void* rb    = d_in[2];
    const void* fc1_w = d_in[3];
    const void* fc1_b = d_in[4];
    const void* fc2_w = d_in[5];
    const void* fc2_b = d_in[6];

    char* ws = (char*)d_ws;
    size_t off = 0;
    auto take = [&](size_t bytes) -> char* {
        char* p = ws + off;
        off = (off + bytes + 255) & ~(size_t)255;
        return p;
    };
    u32* flag     = (u32*)take(4);
    u32* counts   = (u32*)take(NEXP * 4);
    u32* offsets  = (u32*)take(NEXP * 4);
    u16* list     = (u16*)take((size_t)NEXP * NTOK * 2);
    u32* tok_e    = (u32*)take((size_t)NTOK * 2 * 4);
    u32* tok_pos  = (u32*)take((size_t)NTOK * 2 * 4);
    float* tok_w  = (float*)take((size_t)NTOK * 2 * 4);
    u16* a_packed = (u16*)take((size_t)2 * NTOK * HDIM * 2);   // 16 MB
    u16* y_pack   = (u16*)take((size_t)2 * NTOK * DDIM * 2);   // 8 MB
    (void)ws_size; (void)in_sizes; (void)n_in; (void)out_size;

    detect_kernel<<<1, 64, 0, stream>>>((const u16*)x, flag, counts);

    router_kernel<0><<<NTOK / 64, 256, 0, stream>>>(flag, x, rw, rb, counts, list, tok_e, tok_pos, tok_w);
    router_kernel<1><<<NTOK / 64, 256, 0, stream>>>(flag, x, rw, rb, counts, list, tok_e, tok_pos, tok_w);

    prefix_kernel<<<1, 64, 0, stream>>>(counts, offsets);

    fc1_swiglu_kernel<0><<<4096, 256, 0, stream>>>(flag, x, fc1_w, fc1_b, counts, offsets, list, a_packed);
    fc1_swiglu_kernel<1><<<4096, 256, 0, stream>>>(flag, x, fc1_w, fc1_b, counts, offsets, list, a_packed);

    fc2_kernel<0><<<2048, 256, 0, stream>>>(flag, a_packed, fc2_w, fc2_b, counts, offsets, y_pack);
    fc2_kernel<1><<<2048, 256, 0, stream>>>(flag, a_packed, fc2_w, fc2_b, counts, offsets, y_pack);

    combine_kernel<0><<<NTOK, 256, 0, stream>>>(flag, y_pack, offsets, tok_e, tok_pos, tok_w, d_out);
    combine_kernel<1><<<NTOK, 256, 0, stream>>>(flag, y_pack, offsets, tok_e, tok_pos, tok_w, d_out);
}

// Round 10
// 248.724 us; speedup vs baseline: 1.0461x; 1.0461x over previous
//
#include <hip/hip_runtime.h>

typedef unsigned int u32;
typedef unsigned short u16;
typedef unsigned long long u64;

#define NTOK 4096
#define DDIM 512
#define NEXP 8
#define HDIM 1024

typedef __attribute__((ext_vector_type(8))) __bf16 bf16x8;
typedef __attribute__((ext_vector_type(4))) float f32x4;

__device__ __forceinline__ float b2f(u16 u) {
    union { u32 i; float f; } v; v.i = ((u32)u) << 16; return v.f;
}
__device__ __forceinline__ u16 f2b(float f) {
    u32 x = __builtin_bit_cast(u32, f);
    x += 0x7fffu + ((x >> 16) & 1u);
    return (u16)(x >> 16);
}

// MODE 0 = tensors are bf16 in memory; MODE 1 = tensors are f32 in memory.
// SETTLED (round 4 vs 5, round 9 A/B): tensors are f32 -> MODE 1 is live.
template<int MODE>
__device__ __forceinline__ float ldf(const void* p, size_t i) {
    return MODE ? ((const float*)p)[i] : b2f(((const u16*)p)[i]);
}

template<int MODE>
__device__ __forceinline__ void load16(const void* base, size_t elem, uint4& lo, uint4& hi) {
    if (MODE == 0) {
        const uint4* p = (const uint4*)((const u16*)base + elem);
        lo = p[0]; hi = p[1];
    } else {
        const float4* p = (const float4*)((const float*)base + elem);
        const float4 a = p[0], b = p[1], c = p[2], d = p[3];
        union { u16 t[16]; uint4 v[2]; } u;
        u.t[0] = f2b(a.x); u.t[1] = f2b(a.y); u.t[2]  = f2b(a.z); u.t[3]  = f2b(a.w);
        u.t[4] = f2b(b.x); u.t[5] = f2b(b.y); u.t[6]  = f2b(b.z); u.t[7]  = f2b(b.w);
        u.t[8] = f2b(c.x); u.t[9] = f2b(c.y); u.t[10] = f2b(c.z); u.t[11] = f2b(c.w);
        u.t[12] = f2b(d.x); u.t[13] = f2b(d.y); u.t[14] = f2b(d.z); u.t[15] = f2b(d.w);
        lo = u.v[0]; hi = u.v[1];
    }
}

// ---------------- K0: detect dtype + zero expert counts ----------------
__global__ void detect_kernel(const u16* __restrict__ x, u32* __restrict__ flag,
                              u32* __restrict__ counts) {
    const int lane = threadIdx.x & 63;
    const u16 v = x[lane * 2];
    const int ex = (v >> 7) & 0xFF;
    const bool ok = (ex >= 97 && ex <= 140);   // |val| in [2^-30, 2^14]
    const u64 m = __ballot(ok);
    if (threadIdx.x == 0) *flag = (__popcll(m) >= 32) ? 0u : 1u;
    if (threadIdx.x < NEXP) counts[threadIdx.x] = 0;
}

// ---------------- K1: router (64 tokens/block, LDS-aggregated atomics) ----------------
template<int MODE>
__global__ __launch_bounds__(256) void router_kernel(
    const u32* __restrict__ flag,
    const void* __restrict__ x, const void* __restrict__ rw, const void* __restrict__ rb,
    u32* __restrict__ counts, u16* __restrict__ list,
    u32* __restrict__ tok_e, u32* __restrict__ tok_pos, float* __restrict__ tok_w)
{
    if (*flag != (u32)MODE) return;
    __shared__ u32 bcount[NEXP];
    __shared__ u32 bbase[NEXP];
    __shared__ u32 srank[128];
    __shared__ u16 sexp[128];

    const int tid = threadIdx.x;
    const int lane = tid & 63;
    const int wave = tid >> 6;
    if (tid < NEXP) bcount[tid] = 0;

    float wreg[NEXP][8];
#pragma unroll
    for (int e = 0; e < NEXP; e++) {
        if (MODE == 0) {
            const uint4 wv = ((const uint4*)((const u16*)rw + e * DDIM))[lane];
            const u16* wp = (const u16*)&wv;
#pragma unroll
            for (int i = 0; i < 8; i++) wreg[e][i] = b2f(wp[i]);
        } else {
            const float4* p = (const float4*)((const float*)rw + e * DDIM + lane * 8);
            const float4 a = p[0], b = p[1];
            wreg[e][0] = a.x; wreg[e][1] = a.y; wreg[e][2] = a.z; wreg[e][3] = a.w;
            wreg[e][4] = b.x; wreg[e][5] = b.y; wreg[e][6] = b.z; wreg[e][7] = b.w;
        }
    }
    float bias[NEXP];
#pragma unroll
    for (int e = 0; e < NEXP; e++) bias[e] = ldf<MODE>(rb, e);

    __syncthreads();

    const int t0 = blockIdx.x * 64;
    for (int tk = 0; tk < 16; tk++) {
        const int lt = wave * 16 + tk;
        const int t = t0 + lt;
        float xf[8];
        if (MODE == 0) {
            const uint4 xv = ((const uint4*)((const u16*)x + (size_t)t * DDIM))[lane];
            const u16* xs = (const u16*)&xv;
#pragma unroll
            for (int i = 0; i < 8; i++) xf[i] = b2f(xs[i]);
        } else {
            const float4* p = (const float4*)((const float*)x + (size_t)t * DDIM + lane * 8);
            const float4 a = p[0], b = p[1];
            xf[0] = a.x; xf[1] = a.y; xf[2] = a.z; xf[3] = a.w;
            xf[4] = b.x; xf[5] = b.y; xf[6] = b.z; xf[7] = b.w;
        }
        float acc[NEXP];
#pragma unroll
        for (int e = 0; e < NEXP; e++) {
            float s = 0.f;
#pragma unroll
            for (int i = 0; i < 8; i++) s += xf[i] * wreg[e][i];
            acc[e] = s;
        }
#pragma unroll
        for (int off = 32; off > 0; off >>= 1) {
#pragma unroll
            for (int e = 0; e < NEXP; e++) acc[e] += __shfl_xor(acc[e], off, 64);
        }
        if (lane == 0) {
#pragma unroll
            for (int e = 0; e < NEXP; e++) acc[e] += bias[e];
            int e0 = 0;
#pragma unroll
            for (int e = 1; e < NEXP; e++) if (acc[e] > acc[e0]) e0 = e;
            int e1 = -1;
#pragma unroll
            for (int e = 0; e < NEXP; e++) {
                if (e == e0) continue;
                if (e1 < 0 || acc[e] > acc[e1]) e1 = e;
            }
            const float w1v = 1.f / (1.f + __expf(acc[e0] - acc[e1]));
            tok_e[t * 2] = (u32)e0;      tok_w[t * 2] = 1.f - w1v;
            tok_e[t * 2 + 1] = (u32)e1;  tok_w[t * 2 + 1] = w1v;
            sexp[lt * 2] = (u16)e0;
            sexp[lt * 2 + 1] = (u16)e1;
            srank[lt * 2]     = atomicAdd(&bcount[e0], 1u);
            srank[lt * 2 + 1] = atomicAdd(&bcount[e1], 1u);
        }
    }
    __syncthreads();
    if (tid < NEXP) bbase[tid] = atomicAdd(&counts[tid], bcount[tid]);
    __syncthreads();
    if (tid < 128) {
        const int s = tid;
        const int lt = s >> 1;
        const int t = t0 + lt;
        const u32 e = (u32)sexp[s];
        const u32 pos = bbase[e] + srank[s];
        list[e * NTOK + pos] = (u16)t;
        tok_pos[t * 2 + (s & 1)] = pos;
    }
}

// ---------------- K2: exclusive prefix over 8 counts ----------------
__global__ void prefix_kernel(const u32* __restrict__ counts, u32* __restrict__ offsets) {
    if (threadIdx.x == 0) {
        u32 o = 0;
        for (int e = 0; e < NEXP; e++) { offsets[e] = o; o += counts[e]; }
    }
}

// ---------------- K3: gathered fc1 + SwiGLU, 128x64 tile, prefetched ----------------
template<int MODE>
__global__ __launch_bounds__(256, 3) void fc1_swiglu_kernel(
    const u32* __restrict__ flag,
    const void* __restrict__ x, const void* __restrict__ fc1_w, const void* __restrict__ fc1_b,
    const u32* __restrict__ counts, const u32* __restrict__ offsets,
    const u16* __restrict__ list, u16* __restrict__ a_packed)
{
    if (*flag != (u32)MODE) return;
    const int e = blockIdx.z;
    const int cnt = (int)counts[e];
    const int row0 = blockIdx.y * 128;
    if (row0 >= cnt) return;
    const int n0 = blockIdx.x * 64;

    __shared__ u16 As[128 * 64], B1s[64 * 64], B2s[64 * 64];

    const int tid = threadIdx.x;
    const int lr = tid >> 2;
    const int lcc = tid & 3;
    const int lc = lcc * 16;

    int ar0 = row0 + lr;       if (ar0 >= cnt) ar0 = cnt - 1;
    int ar1 = row0 + 64 + lr;  if (ar1 >= cnt) ar1 = cnt - 1;
    const int tok0 = min((int)list[e * NTOK + ar0], NTOK - 1);
    const int tok1 = min((int)list[e * NTOK + ar1], NTOK - 1);
    const size_t a_base0 = (size_t)tok0 * DDIM;
    const size_t a_base1 = (size_t)tok1 * DDIM;
    const size_t b1_base = ((size_t)e * 2 * HDIM + (size_t)(n0 + lr)) * DDIM;
    const size_t b2_base = ((size_t)e * 2 * HDIM + (size_t)(n0 + HDIM + lr)) * DDIM;

    const int sw = lr & 7;
    const int c0 = lcc * 2;
    u16* as0a = &As[lr * 64 + ((c0 ^ sw) << 3)];
    u16* as0b = &As[lr * 64 + (((c0 + 1) ^ sw) << 3)];
    u16* as1a = &As[(lr + 64) * 64 + ((c0 ^ sw) << 3)];
    u16* as1b = &As[(lr + 64) * 64 + (((c0 + 1) ^ sw) << 3)];
    u16* b1a  = &B1s[lr * 64 + ((c0 ^ sw) << 3)];
    u16* b1b  = &B1s[lr * 64 + (((c0 + 1) ^ sw) << 3)];
    u16* b2a  = &B2s[lr * 64 + ((c0 ^ sw) << 3)];
    u16* b2b  = &B2s[lr * 64 + (((c0 + 1) ^ sw) << 3)];

    const int wave = tid >> 6, lane = tid & 63;
    const int mrow0 = (wave >> 1) * 64;
    const int ncol0 = (wave & 1) * 32;
    const int mm = lane & 15;
    const int qb = lane >> 4;
    const int msw = mm & 7;

    f32x4 acc1[4][2], acc2[4][2];
#pragma unroll
    for (int mt = 0; mt < 4; mt++)
#pragma unroll
        for (int nt = 0; nt < 2; nt++) {
            acc1[mt][nt] = f32x4{0, 0, 0, 0};
            acc2[mt][nt] = f32x4{0, 0, 0, 0};
        }

    uint4 A0l, A0h, A1l, A1h, B1l, B1h, B2l, B2h;
    load16<MODE>(x,     a_base0 + lc, A0l, A0h);
    load16<MODE>(x,     a_base1 + lc, A1l, A1h);
    load16<MODE>(fc1_w, b1_base + lc, B1l, B1h);
    load16<MODE>(fc1_w, b2_base + lc, B2l, B2h);

    for (int k0 = 0; k0 < DDIM; k0 += 64) {
        __syncthreads();
        *(uint4*)as0a = A0l; *(uint4*)as0b = A0h;
        *(uint4*)as1a = A1l; *(uint4*)as1b = A1h;
        *(uint4*)b1a  = B1l; *(uint4*)b1b  = B1h;
        *(uint4*)b2a  = B2l; *(uint4*)b2b  = B2h;
        __syncthreads();
        if (k0 + 64 < DDIM) {
            load16<MODE>(x,     a_base0 + k0 + 64 + lc, A0l, A0h);
            load16<MODE>(x,     a_base1 + k0 + 64 + lc, A1l, A1h);
            load16<MODE>(fc1_w, b1_base + k0 + 64 + lc, B1l, B1h);
            load16<MODE>(fc1_w, b2_base + k0 + 64 + lc, B2l, B2h);
        }
#pragma unroll
        for (int kk = 0; kk < 2; kk++) {
            const int g = kk * 4 + qb;
            bf16x8 af[4];
#pragma unroll
            for (int mt = 0; mt < 4; mt++)
                af[mt] = *(const bf16x8*)(&As[(mrow0 + mt * 16 + mm) * 64 + ((g ^ msw) << 3)]);
#pragma unroll
            for (int nt = 0; nt < 2; nt++) {
                const bf16x8 b1f = *(const bf16x8*)(&B1s[(ncol0 + nt * 16 + mm) * 64 + ((g ^ msw) << 3)]);
                const bf16x8 b2f = *(const bf16x8*)(&B2s[(ncol0 + nt * 16 + mm) * 64 + ((g ^ msw) << 3)]);
#pragma unroll
                for (int mt = 0; mt < 4; mt++) {
                    acc1[mt][nt] = __builtin_amdgcn_mfma_f32_16x16x32_bf16(af[mt], b1f, acc1[mt][nt], 0, 0, 0);
                    acc2[mt][nt] = __builtin_amdgcn_mfma_f32_16x16x32_bf16(af[mt], b2f, acc2[mt][nt], 0, 0, 0);
                }
            }
        }
    }

    const u32 obase = offsets[e];
    const int rbv = qb * 4;
#pragma unroll
    for (int nt = 0; nt < 2; nt++) {
        const int n = n0 + ncol0 + nt * 16 + mm;
        const float bb1 = ldf<MODE>(fc1_b, (size_t)e * 2 * HDIM + n);
        const float bb2 = ldf<MODE>(fc1_b, (size_t)e * 2 * HDIM + HDIM + n);
#pragma unroll
        for (int mt = 0; mt < 4; mt++) {
#pragma unroll
            for (int r = 0; r < 4; r++) {
                const int gr = row0 + mrow0 + mt * 16 + rbv + r;
                if (gr < cnt) {
                    const float h1 = acc1[mt][nt][r] + bb1;
                    const float h2 = acc2[mt][nt][r] + bb2;
                    const float av = h1 / (1.f + __expf(-h1)) * h2;
                    a_packed[(size_t)(obase + (u32)gr) * HDIM + n] = f2b(av);
                }
            }
        }
    }
}

// ---------------- K4: fc2, 128x64 tile, prefetched ----------------
template<int MODE>
__global__ __launch_bounds__(256, 3) void fc2_kernel(
    const u32* __restrict__ flag,
    const u16* __restrict__ a_packed, const void* __restrict__ fc2_w, const void* __restrict__ fc2_b,
    const u32* __restrict__ counts, const u32* __restrict__ offsets,
    u16* __restrict__ y_packed)
{
    if (*flag != (u32)MODE) return;
    const int e = blockIdx.z;
    const int cnt = (int)counts[e];
    const int row0 = blockIdx.y * 128;
    if (row0 >= cnt) return;
    const int d0 = blockIdx.x * 64;

    __shared__ u16 As[128 * 64], Bs[64 * 64];

    const int tid = threadIdx.x;
    const int lr = tid >> 2;
    const int lcc = tid & 3;
    const int lc = lcc * 16;
    const u32 obase = offsets[e];

    int ar0 = row0 + lr;       if (ar0 >= cnt) ar0 = cnt - 1;
    int ar1 = row0 + 64 + lr;  if (ar1 >= cnt) ar1 = cnt - 1;
    const size_t a_base0 = (size_t)(obase + (u32)ar0) * HDIM;
    const size_t a_base1 = (size_t)(obase + (u32)ar1) * HDIM;
    const size_t b_base  = ((size_t)e * DDIM + (size_t)(d0 + lr)) * HDIM;

    const int sw = lr & 7;
    const int c0 = lcc * 2;
    u16* as0a = &As[lr * 64 + ((c0 ^ sw) << 3)];
    u16* as0b = &As[lr * 64 + (((c0 + 1) ^ sw) << 3)];
    u16* as1a = &As[(lr + 64) * 64 + ((c0 ^ sw) << 3)];
    u16* as1b = &As[(lr + 64) * 64 + (((c0 + 1) ^ sw) << 3)];
    u16* bsa  = &Bs[lr * 64 + ((c0 ^ sw) << 3)];
    u16* bsb  = &Bs[lr * 64 + (((c0 + 1) ^ sw) << 3)];

    const int wave = tid >> 6, lane = tid & 63;
    const int mrow0 = (wave >> 1) * 64;
    const int ncol0 = (wave & 1) * 32;
    const int mm = lane & 15;
    const int qb = lane >> 4;
    const int msw = mm & 7;

    f32x4 acc[4][2];
#pragma unroll
    for (int mt = 0; mt < 4; mt++)
#pragma unroll
        for (int nt = 0; nt < 2; nt++) acc[mt][nt] = f32x4{0, 0, 0, 0};

    uint4 A0l, A0h, A1l, A1h, Bl, Bh;
    load16<0>(a_packed, a_base0 + lc, A0l, A0h);
    load16<0>(a_packed, a_base1 + lc, A1l, A1h);
    load16<MODE>(fc2_w, b_base + lc, Bl, Bh);

    for (int k0 = 0; k0 < HDIM; k0 += 64) {
        __syncthreads();
        *(uint4*)as0a = A0l; *(uint4*)as0b = A0h;
        *(uint4*)as1a = A1l; *(uint4*)as1b = A1h;
        *(uint4*)bsa  = Bl;  *(uint4*)bsb  = Bh;
        __syncthreads();
        if (k0 + 64 < HDIM) {
            load16<0>(a_packed, a_base0 + k0 + 64 + lc, A0l, A0h);
            load16<0>(a_packed, a_base1 + k0 + 64 + lc, A1l, A1h);
            load16<MODE>(fc2_w, b_base + k0 + 64 + lc, Bl, Bh);
        }
#pragma unroll
        for (int kk = 0; kk < 2; kk++) {
            const int g = kk * 4 + qb;
            bf16x8 af[4];
#pragma unroll
            for (int mt = 0; mt < 4; mt++)
                af[mt] = *(const bf16x8*)(&As[(mrow0 + mt * 16 + mm) * 64 + ((g ^ msw) << 3)]);
#pragma unroll
            for (int nt = 0; nt < 2; nt++) {
                const bf16x8 bfv = *(const bf16x8*)(&Bs[(ncol0 + nt * 16 + mm) * 64 + ((g ^ msw) << 3)]);
#pragma unroll
                for (int mt = 0; mt < 4; mt++)
                    acc[mt][nt] = __builtin_amdgcn_mfma_f32_16x16x32_bf16(af[mt], bfv, acc[mt][nt], 0, 0, 0);
            }
        }
    }

    const int rbv = qb * 4;
#pragma unroll
    for (int nt = 0; nt < 2; nt++) {
        const int n = d0 + ncol0 + nt * 16 + mm;
        const float bb = ldf<MODE>(fc2_b, (size_t)e * DDIM + n);
#pragma unroll
        for (int mt = 0; mt < 4; mt++) {
#pragma unroll
            for (int r = 0; r < 4; r++) {
                const int gr = row0 + mrow0 + mt * 16 + rbv + r;
                if (gr < cnt) {
                    y_packed[(size_t)(obase + (u32)gr) * DDIM + n] = f2b(acc[mt][nt][r] + bb);
                }
            }
        }
    }
}

// ---------------- K5: weighted combine ----------------
template<int MODE>
__global__ __launch_bounds__(256) void combine_kernel(
    const u32* __restrict__ flag,
    const u16* __restrict__ y_packed, const u32* __restrict__ offsets,
    const u32* __restrict__ tok_e, const u32* __restrict__ tok_pos,
    const float* __restrict__ tok_w, void* __restrict__ out)
{
    if (*flag != (u32)MODE) return;
    const int t = blockIdx.x;
    const u32 e0 = tok_e[t * 2] & 7u, e1 = tok_e[t * 2 + 1] & 7u;
    const u32 p0 = min(offsets[e0] + tok_pos[t * 2], (u32)(2 * NTOK - 1));
    const u32 p1 = min(offsets[e1] + tok_pos[t * 2 + 1], (u32)(2 * NTOK - 1));
    const float w0 = tok_w[t * 2], w1 = tok_w[t * 2 + 1];
    const u16* y0 = y_packed + (size_t)p0 * DDIM;
    const u16* y1 = y_packed + (size_t)p1 * DDIM;
    for (int c = threadIdx.x; c < DDIM; c += 256) {
        const float v = w0 * b2f(y0[c]) + w1 * b2f(y1[c]);
        if (MODE == 0) ((u16*)out)[(size_t)t * DDIM + c] = f2b(v);
        else           ((float*)out)[(size_t)t * DDIM + c] = v;
    }
}

extern "C" void kernel_launch(void* const* d_in, const int* in_sizes, int n_in,
                              void* d_out, int out_size, void* d_ws, size_t ws_size,
                              hipStream_t stream)
{
    const void* x     = d_in[0];
    const void* rw    = d_in[1];
    const void* rb    = d_in[2];
    const void* fc1_w = d_in[3];
    const void* fc1_b = d_in[4];
    const void* fc2_w = d_in[5];
    const void* fc2_b = d_in[6];

    char* ws = (char*)d_ws;
    size_t off = 0;
    auto take = [&](size_t bytes) -> char* {
        char* p = ws + off;
        off = (off + bytes + 255) & ~(size_t)255;
        return p;
    };
    u32* flag     = (u32*)take(4);
    u32* counts   = (u32*)take(NEXP * 4);
    u32* offsets  = (u32*)take(NEXP * 4);
    u16* list     = (u16*)take((size_t)NEXP * NTOK * 2);
    u32* tok_e    = (u32*)take((size_t)NTOK * 2 * 4);
    u32* tok_pos  = (u32*)take((size_t)NTOK * 2 * 4);
    float* tok_w  = (float*)take((size_t)NTOK * 2 * 4);
    u16* a_packed = (u16*)take((size_t)2 * NTOK * HDIM * 2);   // 16 MB
    u16* y_pack   = (u16*)take((size_t)2 * NTOK * DDIM * 2);   // 8 MB
    (void)ws_size; (void)in_sizes; (void)n_in; (void)out_size;

    detect_kernel<<<1, 64, 0, stream>>>((const u16*)x, flag, counts);

    router_kernel<1><<<NTOK / 64, 256, 0, stream>>>(flag, x, rw, rb, counts, list, tok_e, tok_pos, tok_w);

    prefix_kernel<<<1, 64, 0, stream>>>(counts, offsets);

    const dim3 g1(HDIM / 64, NTOK / 128, NEXP);
    fc1_swiglu_kernel<1><<<g1, 256, 0, stream>>>(flag, x, fc1_w, fc1_b, counts, offsets, list, a_packed);

    const dim3 g2(DDIM / 64, NTOK / 128, NEXP);
    fc2_kernel<1><<<g2, 256, 0, stream>>>(flag, a_packed, fc2_w, fc2_b, counts, offsets, y_pack);

    combine_kernel<1><<<NTOK, 256, 0, stream>>>(flag, y_pack, offsets, tok_e, tok_pos, tok_w, d_out);
}

// Round 11
// 217.363 us; speedup vs baseline: 1.1971x; 1.1443x over previous
//
#include <hip/hip_runtime.h>

typedef unsigned int u32;
typedef unsigned short u16;
typedef unsigned long long u64;

#define NTOK 4096
#define DDIM 512
#define NEXP 8
#define HDIM 1024

typedef __attribute__((ext_vector_type(8))) __bf16 bf16x8;
typedef __attribute__((ext_vector_type(4))) float f32x4;

__device__ __forceinline__ float b2f(u16 u) {
    union { u32 i; float f; } v; v.i = ((u32)u) << 16; return v.f;
}
__device__ __forceinline__ u16 f2b(float f) {
    u32 x = __builtin_bit_cast(u32, f);
    x += 0x7fffu + ((x >> 16) & 1u);
    return (u16)(x >> 16);
}

// MODE 0 = bf16 in memory; MODE 1 = f32 in memory.
// SETTLED (round 9/10 A/B): harness tensors are f32. MODE 0 is used for the
// pre-converted bf16 ws copies (bit-identical math to per-tile conversion).
template<int MODE>
__device__ __forceinline__ float ldf(const void* p, size_t i) {
    return MODE ? ((const float*)p)[i] : b2f(((const u16*)p)[i]);
}

template<int MODE>
__device__ __forceinline__ void load16(const void* base, size_t elem, uint4& lo, uint4& hi) {
    if (MODE == 0) {
        const uint4* p = (const uint4*)((const u16*)base + elem);
        lo = p[0]; hi = p[1];
    } else {
        const float4* p = (const float4*)((const float*)base + elem);
        const float4 a = p[0], b = p[1], c = p[2], d = p[3];
        union { u16 t[16]; uint4 v[2]; } u;
        u.t[0] = f2b(a.x); u.t[1] = f2b(a.y); u.t[2]  = f2b(a.z); u.t[3]  = f2b(a.w);
        u.t[4] = f2b(b.x); u.t[5] = f2b(b.y); u.t[6]  = f2b(b.z); u.t[7]  = f2b(b.w);
        u.t[8] = f2b(c.x); u.t[9] = f2b(c.y); u.t[10] = f2b(c.z); u.t[11] = f2b(c.w);
        u.t[12] = f2b(d.x); u.t[13] = f2b(d.y); u.t[14] = f2b(d.z); u.t[15] = f2b(d.w);
        lo = u.v[0]; hi = u.v[1];
    }
}

// ---------------- K0: flags + zero expert counts ----------------
__global__ void detect_kernel(const u16* __restrict__ x, u32* __restrict__ flag,
                              u32* __restrict__ zflag, u32* __restrict__ counts) {
    const int lane = threadIdx.x & 63;
    const u16 v = x[lane * 2];
    const int ex = (v >> 7) & 0xFF;
    const bool ok = (ex >= 97 && ex <= 140);
    const u64 m = __ballot(ok);
    if (threadIdx.x == 0) { *flag = (__popcll(m) >= 32) ? 0u : 1u; *zflag = 0u; }
    if (threadIdx.x < NEXP) counts[threadIdx.x] = 0;
}

// ---------------- K0b: one-shot f32 -> bf16 conversion of x + weights + biases ----------------
#define CN0 ((size_t)NTOK * DDIM)                  // x        2,097,152
#define CN1 (CN0 + (size_t)NEXP * 2 * HDIM * DDIM) // fc1_w   +8,388,608
#define CN2 (CN1 + (size_t)NEXP * 2 * HDIM)        // fc1_b   +16,384
#define CN3 (CN2 + (size_t)NEXP * DDIM * HDIM)     // fc2_w   +4,194,304
#define CN4 (CN3 + (size_t)NEXP * DDIM)            // fc2_b   +4,096  => 14,700,544
#define CONV_BLOCKS 7178                            // exactly CN4/8/256

__global__ __launch_bounds__(256) void convert_kernel(
    const float* __restrict__ x,  const float* __restrict__ w1, const float* __restrict__ b1,
    const float* __restrict__ w2, const float* __restrict__ b2,
    u16* __restrict__ xb, u16* __restrict__ w1b, u16* __restrict__ b1b,
    u16* __restrict__ w2b, u16* __restrict__ b2b)
{
    const size_t i = ((size_t)blockIdx.x * 256 + threadIdx.x) * 8;
    if (i >= CN4) return;
    const float* src; u16* dst; size_t off;
    if (i < CN0)      { src = x;  dst = xb;  off = i; }
    else if (i < CN1) { src = w1; dst = w1b; off = i - CN0; }
    else if (i < CN2) { src = b1; dst = b1b; off = i - CN1; }
    else if (i < CN3) { src = w2; dst = w2b; off = i - CN2; }
    else              { src = b2; dst = b2b; off = i - CN3; }
    const float4 a = *(const float4*)(src + off);
    const float4 b = *(const float4*)(src + off + 4);
    union { u16 t[8]; uint4 v; } u;
    u.t[0] = f2b(a.x); u.t[1] = f2b(a.y); u.t[2] = f2b(a.z); u.t[3] = f2b(a.w);
    u.t[4] = f2b(b.x); u.t[5] = f2b(b.y); u.t[6] = f2b(b.z); u.t[7] = f2b(b.w);
    *(uint4*)(dst + off) = u.v;
}

// ---------------- K1: router (64 tokens/block, LDS-aggregated atomics) ----------------
template<int MODE>
__global__ __launch_bounds__(256) void router_kernel(
    const u32* __restrict__ flag,
    const void* __restrict__ x, const void* __restrict__ rw, const void* __restrict__ rb,
    u32* __restrict__ counts, u16* __restrict__ list,
    u32* __restrict__ tok_e, u32* __restrict__ tok_pos, float* __restrict__ tok_w)
{
    if (*flag != (u32)MODE) return;
    __shared__ u32 bcount[NEXP];
    __shared__ u32 bbase[NEXP];
    __shared__ u32 srank[128];
    __shared__ u16 sexp[128];

    const int tid = threadIdx.x;
    const int lane = tid & 63;
    const int wave = tid >> 6;
    if (tid < NEXP) bcount[tid] = 0;

    float wreg[NEXP][8];
#pragma unroll
    for (int e = 0; e < NEXP; e++) {
        if (MODE == 0) {
            const uint4 wv = ((const uint4*)((const u16*)rw + e * DDIM))[lane];
            const u16* wp = (const u16*)&wv;
#pragma unroll
            for (int i = 0; i < 8; i++) wreg[e][i] = b2f(wp[i]);
        } else {
            const float4* p = (const float4*)((const float*)rw + e * DDIM + lane * 8);
            const float4 a = p[0], b = p[1];
            wreg[e][0] = a.x; wreg[e][1] = a.y; wreg[e][2] = a.z; wreg[e][3] = a.w;
            wreg[e][4] = b.x; wreg[e][5] = b.y; wreg[e][6] = b.z; wreg[e][7] = b.w;
        }
    }
    float bias[NEXP];
#pragma unroll
    for (int e = 0; e < NEXP; e++) bias[e] = ldf<MODE>(rb, e);

    __syncthreads();

    const int t0 = blockIdx.x * 64;
    for (int tk = 0; tk < 16; tk++) {
        const int lt = wave * 16 + tk;
        const int t = t0 + lt;
        float xf[8];
        if (MODE == 0) {
            const uint4 xv = ((const uint4*)((const u16*)x + (size_t)t * DDIM))[lane];
            const u16* xs = (const u16*)&xv;
#pragma unroll
            for (int i = 0; i < 8; i++) xf[i] = b2f(xs[i]);
        } else {
            const float4* p = (const float4*)((const float*)x + (size_t)t * DDIM + lane * 8);
            const float4 a = p[0], b = p[1];
            xf[0] = a.x; xf[1] = a.y; xf[2] = a.z; xf[3] = a.w;
            xf[4] = b.x; xf[5] = b.y; xf[6] = b.z; xf[7] = b.w;
        }
        float acc[NEXP];
#pragma unroll
        for (int e = 0; e < NEXP; e++) {
            float s = 0.f;
#pragma unroll
            for (int i = 0; i < 8; i++) s += xf[i] * wreg[e][i];
            acc[e] = s;
        }
#pragma unroll
        for (int off = 32; off > 0; off >>= 1) {
#pragma unroll
            for (int e = 0; e < NEXP; e++) acc[e] += __shfl_xor(acc[e], off, 64);
        }
        if (lane == 0) {
#pragma unroll
            for (int e = 0; e < NEXP; e++) acc[e] += bias[e];
            int e0 = 0;
#pragma unroll
            for (int e = 1; e < NEXP; e++) if (acc[e] > acc[e0]) e0 = e;
            int e1 = -1;
#pragma unroll
            for (int e = 0; e < NEXP; e++) {
                if (e == e0) continue;
                if (e1 < 0 || acc[e] > acc[e1]) e1 = e;
            }
            const float w1v = 1.f / (1.f + __expf(acc[e0] - acc[e1]));
            tok_e[t * 2] = (u32)e0;      tok_w[t * 2] = 1.f - w1v;
            tok_e[t * 2 + 1] = (u32)e1;  tok_w[t * 2 + 1] = w1v;
            sexp[lt * 2] = (u16)e0;
            sexp[lt * 2 + 1] = (u16)e1;
            srank[lt * 2]     = atomicAdd(&bcount[e0], 1u);
            srank[lt * 2 + 1] = atomicAdd(&bcount[e1], 1u);
        }
    }
    __syncthreads();
    if (tid < NEXP) bbase[tid] = atomicAdd(&counts[tid], bcount[tid]);
    __syncthreads();
    if (tid < 128) {
        const int s = tid;
        const int lt = s >> 1;
        const int t = t0 + lt;
        const u32 e = (u32)sexp[s];
        const u32 pos = bbase[e] + srank[s];
        list[e * NTOK + pos] = (u16)t;
        tok_pos[t * 2 + (s & 1)] = pos;
    }
}

// ---------------- K2: exclusive prefix over 8 counts ----------------
__global__ void prefix_kernel(const u32* __restrict__ counts, u32* __restrict__ offsets) {
    if (threadIdx.x == 0) {
        u32 o = 0;
        for (int e = 0; e < NEXP; e++) { offsets[e] = o; o += counts[e]; }
    }
}

// ---------------- K3: gathered fc1 + SwiGLU, 128x64 tile, prefetched ----------------
template<int MODE>
__global__ __launch_bounds__(256, 3) void fc1_swiglu_kernel(
    const u32* __restrict__ flag,
    const void* __restrict__ x, const void* __restrict__ fc1_w, const void* __restrict__ fc1_b,
    const u32* __restrict__ counts, const u32* __restrict__ offsets,
    const u16* __restrict__ list, u16* __restrict__ a_packed)
{
    if (*flag != 0u) return;   // runs unconditionally in both paths (flag arg is a zero word)
    const int e = blockIdx.z;
    const int cnt = (int)counts[e];
    const int row0 = blockIdx.y * 128;
    if (row0 >= cnt) return;
    const int n0 = blockIdx.x * 64;

    __shared__ u16 As[128 * 64], B1s[64 * 64], B2s[64 * 64];

    const int tid = threadIdx.x;
    const int lr = tid >> 2;
    const int lcc = tid & 3;
    const int lc = lcc * 16;

    int ar0 = row0 + lr;       if (ar0 >= cnt) ar0 = cnt - 1;
    int ar1 = row0 + 64 + lr;  if (ar1 >= cnt) ar1 = cnt - 1;
    const int tok0 = min((int)list[e * NTOK + ar0], NTOK - 1);
    const int tok1 = min((int)list[e * NTOK + ar1], NTOK - 1);
    const size_t a_base0 = (size_t)tok0 * DDIM;
    const size_t a_base1 = (size_t)tok1 * DDIM;
    const size_t b1_base = ((size_t)e * 2 * HDIM + (size_t)(n0 + lr)) * DDIM;
    const size_t b2_base = ((size_t)e * 2 * HDIM + (size_t)(n0 + HDIM + lr)) * DDIM;

    const int sw = lr & 7;
    const int c0 = lcc * 2;
    u16* as0a = &As[lr * 64 + ((c0 ^ sw) << 3)];
    u16* as0b = &As[lr * 64 + (((c0 + 1) ^ sw) << 3)];
    u16* as1a = &As[(lr + 64) * 64 + ((c0 ^ sw) << 3)];
    u16* as1b = &As[(lr + 64) * 64 + (((c0 + 1) ^ sw) << 3)];
    u16* b1a  = &B1s[lr * 64 + ((c0 ^ sw) << 3)];
    u16* b1b  = &B1s[lr * 64 + (((c0 + 1) ^ sw) << 3)];
    u16* b2a  = &B2s[lr * 64 + ((c0 ^ sw) << 3)];
    u16* b2b  = &B2s[lr * 64 + (((c0 + 1) ^ sw) << 3)];

    const int wave = tid >> 6, lane = tid & 63;
    const int mrow0 = (wave >> 1) * 64;
    const int ncol0 = (wave & 1) * 32;
    const int mm = lane & 15;
    const int qb = lane >> 4;
    const int msw = mm & 7;

    f32x4 acc1[4][2], acc2[4][2];
#pragma unroll
    for (int mt = 0; mt < 4; mt++)
#pragma unroll
        for (int nt = 0; nt < 2; nt++) {
            acc1[mt][nt] = f32x4{0, 0, 0, 0};
            acc2[mt][nt] = f32x4{0, 0, 0, 0};
        }

    uint4 A0l, A0h, A1l, A1h, B1l, B1h, B2l, B2h;
    load16<MODE>(x,     a_base0 + lc, A0l, A0h);
    load16<MODE>(x,     a_base1 + lc, A1l, A1h);
    load16<MODE>(fc1_w, b1_base + lc, B1l, B1h);
    load16<MODE>(fc1_w, b2_base + lc, B2l, B2h);

    for (int k0 = 0; k0 < DDIM; k0 += 64) {
        __syncthreads();
        *(uint4*)as0a = A0l; *(uint4*)as0b = A0h;
        *(uint4*)as1a = A1l; *(uint4*)as1b = A1h;
        *(uint4*)b1a  = B1l; *(uint4*)b1b  = B1h;
        *(uint4*)b2a  = B2l; *(uint4*)b2b  = B2h;
        __syncthreads();
        if (k0 + 64 < DDIM) {
            load16<MODE>(x,     a_base0 + k0 + 64 + lc, A0l, A0h);
            load16<MODE>(x,     a_base1 + k0 + 64 + lc, A1l, A1h);
            load16<MODE>(fc1_w, b1_base + k0 + 64 + lc, B1l, B1h);
            load16<MODE>(fc1_w, b2_base + k0 + 64 + lc, B2l, B2h);
        }
#pragma unroll
        for (int kk = 0; kk < 2; kk++) {
            const int g = kk * 4 + qb;
            bf16x8 af[4];
#pragma unroll
            for (int mt = 0; mt < 4; mt++)
                af[mt] = *(const bf16x8*)(&As[(mrow0 + mt * 16 + mm) * 64 + ((g ^ msw) << 3)]);
#pragma unroll
            for (int nt = 0; nt < 2; nt++) {
                const bf16x8 b1f = *(const bf16x8*)(&B1s[(ncol0 + nt * 16 + mm) * 64 + ((g ^ msw) << 3)]);
                const bf16x8 b2f = *(const bf16x8*)(&B2s[(ncol0 + nt * 16 + mm) * 64 + ((g ^ msw) << 3)]);
#pragma unroll
                for (int mt = 0; mt < 4; mt++) {
                    acc1[mt][nt] = __builtin_amdgcn_mfma_f32_16x16x32_bf16(af[mt], b1f, acc1[mt][nt], 0, 0, 0);
                    acc2[mt][nt] = __builtin_amdgcn_mfma_f32_16x16x32_bf16(af[mt], b2f, acc2[mt][nt], 0, 0, 0);
                }
            }
        }
    }

    const u32 obase = offsets[e];
    const int rbv = qb * 4;
#pragma unroll
    for (int nt = 0; nt < 2; nt++) {
        const int n = n0 + ncol0 + nt * 16 + mm;
        const float bb1 = ldf<MODE>(fc1_b, (size_t)e * 2 * HDIM + n);
        const float bb2 = ldf<MODE>(fc1_b, (size_t)e * 2 * HDIM + HDIM + n);
#pragma unroll
        for (int mt = 0; mt < 4; mt++) {
#pragma unroll
            for (int r = 0; r < 4; r++) {
                const int gr = row0 + mrow0 + mt * 16 + rbv + r;
                if (gr < cnt) {
                    const float h1 = acc1[mt][nt][r] + bb1;
                    const float h2 = acc2[mt][nt][r] + bb2;
                    const float av = h1 / (1.f + __expf(-h1)) * h2;
                    a_packed[(size_t)(obase + (u32)gr) * HDIM + n] = f2b(av);
                }
            }
        }
    }
}

// ---------------- K4: fc2, 128x64 tile, prefetched ----------------
template<int MODE>
__global__ __launch_bounds__(256, 3) void fc2_kernel(
    const u32* __restrict__ flag,
    const u16* __restrict__ a_packed, const void* __restrict__ fc2_w, const void* __restrict__ fc2_b,
    const u32* __restrict__ counts, const u32* __restrict__ offsets,
    u16* __restrict__ y_packed)
{
    if (*flag != 0u) return;   // zero word in both paths
    const int e = blockIdx.z;
    const int cnt = (int)counts[e];
    const int row0 = blockIdx.y * 128;
    if (row0 >= cnt) return;
    const int d0 = blockIdx.x * 64;

    __shared__ u16 As[128 * 64], Bs[64 * 64];

    const int tid = threadIdx.x;
    const int lr = tid >> 2;
    const int lcc = tid & 3;
    const int lc = lcc * 16;
    const u32 obase = offsets[e];

    int ar0 = row0 + lr;       if (ar0 >= cnt) ar0 = cnt - 1;
    int ar1 = row0 + 64 + lr;  if (ar1 >= cnt) ar1 = cnt - 1;
    const size_t a_base0 = (size_t)(obase + (u32)ar0) * HDIM;
    const size_t a_base1 = (size_t)(obase + (u32)ar1) * HDIM;
    const size_t b_base  = ((size_t)e * DDIM + (size_t)(d0 + lr)) * HDIM;

    const int sw = lr & 7;
    const int c0 = lcc * 2;
    u16* as0a = &As[lr * 64 + ((c0 ^ sw) << 3)];
    u16* as0b = &As[lr * 64 + (((c0 + 1) ^ sw) << 3)];
    u16* as1a = &As[(lr + 64) * 64 + ((c0 ^ sw) << 3)];
    u16* as1b = &As[(lr + 64) * 64 + (((c0 + 1) ^ sw) << 3)];
    u16* bsa  = &Bs[lr * 64 + ((c0 ^ sw) << 3)];
    u16* bsb  = &Bs[lr * 64 + (((c0 + 1) ^ sw) << 3)];

    const int wave = tid >> 6, lane = tid & 63;
    const int mrow0 = (wave >> 1) * 64;
    const int ncol0 = (wave & 1) * 32;
    const int mm = lane & 15;
    const int qb = lane >> 4;
    const int msw = mm & 7;

    f32x4 acc[4][2];
#pragma unroll
    for (int mt = 0; mt < 4; mt++)
#pragma unroll
        for (int nt = 0; nt < 2; nt++) acc[mt][nt] = f32x4{0, 0, 0, 0};

    uint4 A0l, A0h, A1l, A1h, Bl, Bh;
    load16<0>(a_packed, a_base0 + lc, A0l, A0h);
    load16<0>(a_packed, a_base1 + lc, A1l, A1h);
    load16<MODE>(fc2_w, b_base + lc, Bl, Bh);

    for (int k0 = 0; k0 < HDIM; k0 += 64) {
        __syncthreads();
        *(uint4*)as0a = A0l; *(uint4*)as0b = A0h;
        *(uint4*)as1a = A1l; *(uint4*)as1b = A1h;
        *(uint4*)bsa  = Bl;  *(uint4*)bsb  = Bh;
        __syncthreads();
        if (k0 + 64 < HDIM) {
            load16<0>(a_packed, a_base0 + k0 + 64 + lc, A0l, A0h);
            load16<0>(a_packed, a_base1 + k0 + 64 + lc, A1l, A1h);
            load16<MODE>(fc2_w, b_base + k0 + 64 + lc, Bl, Bh);
        }
#pragma unroll
        for (int kk = 0; kk < 2; kk++) {
            const int g = kk * 4 + qb;
            bf16x8 af[4];
#pragma unroll
            for (int mt = 0; mt < 4; mt++)
                af[mt] = *(const bf16x8*)(&As[(mrow0 + mt * 16 + mm) * 64 + ((g ^ msw) << 3)]);
#pragma unroll
            for (int nt = 0; nt < 2; nt++) {
                const bf16x8 bfv = *(const bf16x8*)(&Bs[(ncol0 + nt * 16 + mm) * 64 + ((g ^ msw) << 3)]);
#pragma unroll
                for (int mt = 0; mt < 4; mt++)
                    acc[mt][nt] = __builtin_amdgcn_mfma_f32_16x16x32_bf16(af[mt], bfv, acc[mt][nt], 0, 0, 0);
            }
        }
    }

    const int rbv = qb * 4;
#pragma unroll
    for (int nt = 0; nt < 2; nt++) {
        const int n = d0 + ncol0 + nt * 16 + mm;
        const float bb = ldf<MODE>(fc2_b, (size_t)e * DDIM + n);
#pragma unroll
        for (int mt = 0; mt < 4; mt++) {
#pragma unroll
            for (int r = 0; r < 4; r++) {
                const int gr = row0 + mrow0 + mt * 16 + rbv + r;
                if (gr < cnt) {
                    y_packed[(size_t)(obase + (u32)gr) * DDIM + n] = f2b(acc[mt][nt][r] + bb);
                }
            }
        }
    }
}

// ---------------- K5: weighted combine (writes f32 output) ----------------
template<int MODE>
__global__ __launch_bounds__(256) void combine_kernel(
    const u32* __restrict__ flag,
    const u16* __restrict__ y_packed, const u32* __restrict__ offsets,
    const u32* __restrict__ tok_e, const u32* __restrict__ tok_pos,
    const float* __restrict__ tok_w, void* __restrict__ out)
{
    if (*flag != (u32)MODE) return;
    const int t = blockIdx.x;
    const u32 e0 = tok_e[t * 2] & 7u, e1 = tok_e[t * 2 + 1] & 7u;
    const u32 p0 = min(offsets[e0] + tok_pos[t * 2], (u32)(2 * NTOK - 1));
    const u32 p1 = min(offsets[e1] + tok_pos[t * 2 + 1], (u32)(2 * NTOK - 1));
    const float w0 = tok_w[t * 2], w1 = tok_w[t * 2 + 1];
    const u16* y0 = y_packed + (size_t)p0 * DDIM;
    const u16* y1 = y_packed + (size_t)p1 * DDIM;
    for (int c = threadIdx.x; c < DDIM; c += 256) {
        const float v = w0 * b2f(y0[c]) + w1 * b2f(y1[c]);
        if (MODE == 0) ((u16*)out)[(size_t)t * DDIM + c] = f2b(v);
        else           ((float*)out)[(size_t)t * DDIM + c] = v;
    }
}

extern "C" void kernel_launch(void* const* d_in, const int* in_sizes, int n_in,
                              void* d_out, int out_size, void* d_ws, size_t ws_size,
                              hipStream_t stream)
{
    const void* x     = d_in[0];
    const void* rw    = d_in[1];
    const void* rb    = d_in[2];
    const void* fc1_w = d_in[3];
    const void* fc1_b = d_in[4];
    const void* fc2_w = d_in[5];
    const void* fc2_b = d_in[6];

    char* ws = (char*)d_ws;
    size_t off = 0;
    auto take = [&](size_t bytes) -> char* {
        char* p = ws + off;
        off = (off + bytes + 255) & ~(size_t)255;
        return p;
    };
    u32* flag     = (u32*)take(8);             // [0]=dtype flag, [1]=zero word
    u32* zflag    = flag + 1;
    u32* counts   = (u32*)take(NEXP * 4);
    u32* offsets  = (u32*)take(NEXP * 4);
    u16* list     = (u16*)take((size_t)NEXP * NTOK * 2);
    u32* tok_e    = (u32*)take((size_t)NTOK * 2 * 4);
    u32* tok_pos  = (u32*)take((size_t)NTOK * 2 * 4);
    float* tok_w  = (float*)take((size_t)NTOK * 2 * 4);
    u16* a_packed = (u16*)take((size_t)2 * NTOK * HDIM * 2);   // 16 MB
    u16* y_pack   = (u16*)take((size_t)2 * NTOK * DDIM * 2);   // 8 MB
    // bf16 pre-converted copies (only used if ws_size permits):
    u16* xb  = (u16*)take((size_t)NTOK * DDIM * 2);            // 4 MB
    u16* w1b = (u16*)take((size_t)NEXP * 2 * HDIM * DDIM * 2); // 16.78 MB
    u16* b1b = (u16*)take((size_t)NEXP * 2 * HDIM * 2);
    u16* w2b = (u16*)take((size_t)NEXP * DDIM * HDIM * 2);     // 8.39 MB
    u16* b2b = (u16*)take((size_t)NEXP * DDIM * 2);
    const bool use_conv = (off <= ws_size);
    (void)in_sizes; (void)n_in; (void)out_size;

    detect_kernel<<<1, 64, 0, stream>>>((const u16*)x, flag, zflag, counts);

    router_kernel<1><<<NTOK / 64, 256, 0, stream>>>(flag, x, rw, rb, counts, list, tok_e, tok_pos, tok_w);

    prefix_kernel<<<1, 64, 0, stream>>>(counts, offsets);

    const dim3 g1(HDIM / 64, NTOK / 128, NEXP);
    const dim3 g2(DDIM / 64, NTOK / 128, NEXP);

    if (use_conv) {
        convert_kernel<<<CONV_BLOCKS, 256, 0, stream>>>(
            (const float*)x, (const float*)fc1_w, (const float*)fc1_b,
            (const float*)fc2_w, (const float*)fc2_b, xb, w1b, b1b, w2b, b2b);
        fc1_swiglu_kernel<0><<<g1, 256, 0, stream>>>(zflag, xb, w1b, b1b, counts, offsets, list, a_packed);
        fc2_kernel<0><<<g2, 256, 0, stream>>>(zflag, a_packed, w2b, b2b, counts, offsets, y_pack);
    } else {
        fc1_swiglu_kernel<1><<<g1, 256, 0, stream>>>(zflag, x, fc1_w, fc1_b, counts, offsets, list, a_packed);
        fc2_kernel<1><<<g2, 256, 0, stream>>>(zflag, a_packed, fc2_w, fc2_b, counts, offsets, y_pack);
    }

    combine_kernel<1><<<NTOK, 256, 0, stream>>>(flag, y_pack, offsets, tok_e, tok_pos, tok_w, d_out);
}

// Round 12
// 189.271 us; speedup vs baseline: 1.3747x; 1.1484x over previous
//
#include <hip/hip_runtime.h>

typedef unsigned int u32;
typedef unsigned short u16;
typedef unsigned long long u64;

#define NTOK 4096
#define DDIM 512
#define NEXP 8
#define HDIM 1024

typedef __attribute__((ext_vector_type(8))) __bf16 bf16x8;
typedef __attribute__((ext_vector_type(4))) float f32x4;

__device__ __forceinline__ float b2f(u16 u) {
    union { u32 i; float f; } v; v.i = ((u32)u) << 16; return v.f;
}
__device__ __forceinline__ u16 f2b(float f) {
    u32 x = __builtin_bit_cast(u32, f);
    x += 0x7fffu + ((x >> 16) & 1u);
    return (u16)(x >> 16);
}

// MODE 0 = bf16 in memory; MODE 1 = f32 in memory.
// SETTLED (round 9/10 A/B): harness tensors are f32. MODE 0 is used for the
// pre-converted bf16 ws copies (bit-identical math to per-tile conversion).
template<int MODE>
__device__ __forceinline__ float ldf(const void* p, size_t i) {
    return MODE ? ((const float*)p)[i] : b2f(((const u16*)p)[i]);
}

template<int MODE>
__device__ __forceinline__ void load16(const void* base, size_t elem, uint4& lo, uint4& hi) {
    if (MODE == 0) {
        const uint4* p = (const uint4*)((const u16*)base + elem);
        lo = p[0]; hi = p[1];
    } else {
        const float4* p = (const float4*)((const float*)base + elem);
        const float4 a = p[0], b = p[1], c = p[2], d = p[3];
        union { u16 t[16]; uint4 v[2]; } u;
        u.t[0] = f2b(a.x); u.t[1] = f2b(a.y); u.t[2]  = f2b(a.z); u.t[3]  = f2b(a.w);
        u.t[4] = f2b(b.x); u.t[5] = f2b(b.y); u.t[6]  = f2b(b.z); u.t[7]  = f2b(b.w);
        u.t[8] = f2b(c.x); u.t[9] = f2b(c.y); u.t[10] = f2b(c.z); u.t[11] = f2b(c.w);
        u.t[12] = f2b(d.x); u.t[13] = f2b(d.y); u.t[14] = f2b(d.z); u.t[15] = f2b(d.w);
        lo = u.v[0]; hi = u.v[1];
    }
}

// ---------------- K0: flags + zero expert counts ----------------
__global__ void detect_kernel(const u16* __restrict__ x, u32* __restrict__ flag,
                              u32* __restrict__ zflag, u32* __restrict__ counts) {
    const int lane = threadIdx.x & 63;
    const u16 v = x[lane * 2];
    const int ex = (v >> 7) & 0xFF;
    const bool ok = (ex >= 97 && ex <= 140);
    const u64 m = __ballot(ok);
    if (threadIdx.x == 0) { *flag = (__popcll(m) >= 32) ? 0u : 1u; *zflag = 0u; }
    if (threadIdx.x < NEXP) counts[threadIdx.x] = 0;
}

// ---------------- K0b: one-shot f32 -> bf16 conversion of x + weights + biases ----------------
#define CN0 ((size_t)NTOK * DDIM)                  // x        2,097,152
#define CN1 (CN0 + (size_t)NEXP * 2 * HDIM * DDIM) // fc1_w   +8,388,608
#define CN2 (CN1 + (size_t)NEXP * 2 * HDIM)        // fc1_b   +16,384
#define CN3 (CN2 + (size_t)NEXP * DDIM * HDIM)     // fc2_w   +4,194,304
#define CN4 (CN3 + (size_t)NEXP * DDIM)            // fc2_b   +4,096  => 14,700,544
#define CONV_BLOCKS 7178                            // exactly CN4/8/256

__global__ __launch_bounds__(256) void convert_kernel(
    const float* __restrict__ x,  const float* __restrict__ w1, const float* __restrict__ b1,
    const float* __restrict__ w2, const float* __restrict__ b2,
    u16* __restrict__ xb, u16* __restrict__ w1b, u16* __restrict__ b1b,
    u16* __restrict__ w2b, u16* __restrict__ b2b)
{
    const size_t i = ((size_t)blockIdx.x * 256 + threadIdx.x) * 8;
    if (i >= CN4) return;
    const float* src; u16* dst; size_t off;
    if (i < CN0)      { src = x;  dst = xb;  off = i; }
    else if (i < CN1) { src = w1; dst = w1b; off = i - CN0; }
    else if (i < CN2) { src = b1; dst = b1b; off = i - CN1; }
    else if (i < CN3) { src = w2; dst = w2b; off = i - CN2; }
    else              { src = b2; dst = b2b; off = i - CN3; }
    const float4 a = *(const float4*)(src + off);
    const float4 b = *(const float4*)(src + off + 4);
    union { u16 t[8]; uint4 v; } u;
    u.t[0] = f2b(a.x); u.t[1] = f2b(a.y); u.t[2] = f2b(a.z); u.t[3] = f2b(a.w);
    u.t[4] = f2b(b.x); u.t[5] = f2b(b.y); u.t[6] = f2b(b.z); u.t[7] = f2b(b.w);
    *(uint4*)(dst + off) = u.v;
}

// ---------------- K1: router compute (one wave per token, NO atomics) ----------------
// 4096 waves (1024 blocks) -> x-load latency hidden by TLP; replaces the 64-block
// sequential-16-token version measured at 54us / 2.2% occupancy (round 11).
template<int MODE>
__global__ __launch_bounds__(256) void router_kernel(
    const u32* __restrict__ flag,
    const void* __restrict__ x, const void* __restrict__ rw, const void* __restrict__ rb,
    u16* __restrict__ tok_epack, u32* __restrict__ tok_e, float* __restrict__ tok_w)
{
    if (*flag != (u32)MODE) return;
    const int tid = threadIdx.x;
    const int lane = tid & 63;
    const int t = blockIdx.x * 4 + (tid >> 6);

    float xf[8];
    if (MODE == 0) {
        const uint4 xv = ((const uint4*)((const u16*)x + (size_t)t * DDIM))[lane];
        const u16* xs = (const u16*)&xv;
#pragma unroll
        for (int i = 0; i < 8; i++) xf[i] = b2f(xs[i]);
    } else {
        const float4* p = (const float4*)((const float*)x + (size_t)t * DDIM + lane * 8);
        const float4 a = p[0], b = p[1];
        xf[0] = a.x; xf[1] = a.y; xf[2] = a.z; xf[3] = a.w;
        xf[4] = b.x; xf[5] = b.y; xf[6] = b.z; xf[7] = b.w;
    }

    float acc[NEXP];
#pragma unroll
    for (int e = 0; e < NEXP; e++) {
        float s = 0.f;
        if (MODE == 0) {
            const uint4 wv = ((const uint4*)((const u16*)rw + e * DDIM))[lane];
            const u16* wp = (const u16*)&wv;
#pragma unroll
            for (int i = 0; i < 8; i++) s += xf[i] * b2f(wp[i]);
        } else {
            const float4* p = (const float4*)((const float*)rw + e * DDIM + lane * 8);
            const float4 a = p[0], b = p[1];
            s = xf[0] * a.x + xf[1] * a.y + xf[2] * a.z + xf[3] * a.w
              + xf[4] * b.x + xf[5] * b.y + xf[6] * b.z + xf[7] * b.w;
        }
        acc[e] = s;
    }
#pragma unroll
    for (int off = 32; off > 0; off >>= 1) {
#pragma unroll
        for (int e = 0; e < NEXP; e++) acc[e] += __shfl_xor(acc[e], off, 64);
    }
    if (lane == 0) {
#pragma unroll
        for (int e = 0; e < NEXP; e++) acc[e] += ldf<MODE>(rb, e);
        // top-2, lowest-index tie-break (matches lax.top_k)
        int e0 = 0;
#pragma unroll
        for (int e = 1; e < NEXP; e++) if (acc[e] > acc[e0]) e0 = e;
        int e1 = -1;
#pragma unroll
        for (int e = 0; e < NEXP; e++) {
            if (e == e0) continue;
            if (e1 < 0 || acc[e] > acc[e1]) e1 = e;
        }
        const float w1v = 1.f / (1.f + __expf(acc[e0] - acc[e1]));
        tok_epack[t] = (u16)((u32)e0 | ((u32)e1 << 8));
        tok_e[t * 2] = (u32)e0;      tok_w[t * 2] = 1.f - w1v;
        tok_e[t * 2 + 1] = (u32)e1;  tok_w[t * 2 + 1] = w1v;
    }
}

// ---------------- K2: build per-expert lists (single block, ballot compaction) ----------------
// 8 waves, one per expert; each scans all 4096 tokens from LDS (u32 array, no
// type-punning). Deterministic, zero atomics. Also emits counts + offsets.
__global__ __launch_bounds__(512) void build_lists_kernel(
    const u16* __restrict__ tok_epack,
    u32* __restrict__ counts, u32* __restrict__ offsets,
    u16* __restrict__ list, u32* __restrict__ tok_pos)
{
    __shared__ u32 eLDS[NTOK / 2];   // packed token pairs
    __shared__ u32 cLDS[NEXP];
    const int tid = threadIdx.x;
    for (int i = tid; i < NTOK / 2; i += 512)
        eLDS[i] = ((const u32*)tok_epack)[i];
    __syncthreads();

    const int wave = tid >> 6, lane = tid & 63;
    const u64 ltmask = ((u64)1 << lane) - 1;   // lane<=63, no UB
    const u32 e = (u32)wave;                   // one expert per wave
    u32 r = 0;
    for (int c = 0; c < 64; c++) {
        const int t = c * 64 + lane;
        const u32 pair = eLDS[t >> 1];
        const u32 p = (pair >> ((t & 1) * 16)) & 0xFFFFu;
        const u32 e0 = p & 0xFFu, e1 = (p >> 8) & 0xFFu;
        const u64 m0 = __ballot(e0 == e);
        if (e0 == e) {
            const u32 idx = r + (u32)__popcll(m0 & ltmask);
            list[e * NTOK + idx] = (u16)t;
            tok_pos[t * 2] = idx;
        }
        r += (u32)__popcll(m0);
        const u64 m1 = __ballot(e1 == e);
        if (e1 == e) {
            const u32 idx = r + (u32)__popcll(m1 & ltmask);
            list[e * NTOK + idx] = (u16)t;
            tok_pos[t * 2 + 1] = idx;
        }
        r += (u32)__popcll(m1);
    }
    if (lane == 0) cLDS[e] = r;
    __syncthreads();
    if (tid == 0) {
        u32 o = 0;
        for (int i = 0; i < NEXP; i++) { counts[i] = cLDS[i]; offsets[i] = o; o += cLDS[i]; }
    }
}

// ---------------- K3: gathered fc1 + SwiGLU, 128x64 tile, prefetched ----------------
template<int MODE>
__global__ __launch_bounds__(256, 3) void fc1_swiglu_kernel(
    const u32* __restrict__ flag,
    const void* __restrict__ x, const void* __restrict__ fc1_w, const void* __restrict__ fc1_b,
    const u32* __restrict__ counts, const u32* __restrict__ offsets,
    const u16* __restrict__ list, u16* __restrict__ a_packed)
{
    if (*flag != 0u) return;   // zero word in both paths
    const int e = blockIdx.z;
    const int cnt = (int)counts[e];
    const int row0 = blockIdx.y * 128;
    if (row0 >= cnt) return;
    const int n0 = blockIdx.x * 64;

    __shared__ u16 As[128 * 64], B1s[64 * 64], B2s[64 * 64];

    const int tid = threadIdx.x;
    const int lr = tid >> 2;
    const int lcc = tid & 3;
    const int lc = lcc * 16;

    int ar0 = row0 + lr;       if (ar0 >= cnt) ar0 = cnt - 1;
    int ar1 = row0 + 64 + lr;  if (ar1 >= cnt) ar1 = cnt - 1;
    const int tok0 = min((int)list[e * NTOK + ar0], NTOK - 1);
    const int tok1 = min((int)list[e * NTOK + ar1], NTOK - 1);
    const size_t a_base0 = (size_t)tok0 * DDIM;
    const size_t a_base1 = (size_t)tok1 * DDIM;
    const size_t b1_base = ((size_t)e * 2 * HDIM + (size_t)(n0 + lr)) * DDIM;
    const size_t b2_base = ((size_t)e * 2 * HDIM + (size_t)(n0 + HDIM + lr)) * DDIM;

    const int sw = lr & 7;
    const int c0 = lcc * 2;
    u16* as0a = &As[lr * 64 + ((c0 ^ sw) << 3)];
    u16* as0b = &As[lr * 64 + (((c0 + 1) ^ sw) << 3)];
    u16* as1a = &As[(lr + 64) * 64 + ((c0 ^ sw) << 3)];
    u16* as1b = &As[(lr + 64) * 64 + (((c0 + 1) ^ sw) << 3)];
    u16* b1a  = &B1s[lr * 64 + ((c0 ^ sw) << 3)];
    u16* b1b  = &B1s[lr * 64 + (((c0 + 1) ^ sw) << 3)];
    u16* b2a  = &B2s[lr * 64 + ((c0 ^ sw) << 3)];
    u16* b2b  = &B2s[lr * 64 + (((c0 + 1) ^ sw) << 3)];

    const int wave = tid >> 6, lane = tid & 63;
    const int mrow0 = (wave >> 1) * 64;
    const int ncol0 = (wave & 1) * 32;
    const int mm = lane & 15;
    const int qb = lane >> 4;
    const int msw = mm & 7;

    f32x4 acc1[4][2], acc2[4][2];
#pragma unroll
    for (int mt = 0; mt < 4; mt++)
#pragma unroll
        for (int nt = 0; nt < 2; nt++) {
            acc1[mt][nt] = f32x4{0, 0, 0, 0};
            acc2[mt][nt] = f32x4{0, 0, 0, 0};
        }

    uint4 A0l, A0h, A1l, A1h, B1l, B1h, B2l, B2h;
    load16<MODE>(x,     a_base0 + lc, A0l, A0h);
    load16<MODE>(x,     a_base1 + lc, A1l, A1h);
    load16<MODE>(fc1_w, b1_base + lc, B1l, B1h);
    load16<MODE>(fc1_w, b2_base + lc, B2l, B2h);

    for (int k0 = 0; k0 < DDIM; k0 += 64) {
        __syncthreads();
        *(uint4*)as0a = A0l; *(uint4*)as0b = A0h;
        *(uint4*)as1a = A1l; *(uint4*)as1b = A1h;
        *(uint4*)b1a  = B1l; *(uint4*)b1b  = B1h;
        *(uint4*)b2a  = B2l; *(uint4*)b2b  = B2h;
        __syncthreads();
        if (k0 + 64 < DDIM) {
            load16<MODE>(x,     a_base0 + k0 + 64 + lc, A0l, A0h);
            load16<MODE>(x,     a_base1 + k0 + 64 + lc, A1l, A1h);
            load16<MODE>(fc1_w, b1_base + k0 + 64 + lc, B1l, B1h);
            load16<MODE>(fc1_w, b2_base + k0 + 64 + lc, B2l, B2h);
        }
#pragma unroll
        for (int kk = 0; kk < 2; kk++) {
            const int g = kk * 4 + qb;
            bf16x8 af[4];
#pragma unroll
            for (int mt = 0; mt < 4; mt++)
                af[mt] = *(const bf16x8*)(&As[(mrow0 + mt * 16 + mm) * 64 + ((g ^ msw) << 3)]);
#pragma unroll
            for (int nt = 0; nt < 2; nt++) {
                const bf16x8 b1f = *(const bf16x8*)(&B1s[(ncol0 + nt * 16 + mm) * 64 + ((g ^ msw) << 3)]);
                const bf16x8 b2f = *(const bf16x8*)(&B2s[(ncol0 + nt * 16 + mm) * 64 + ((g ^ msw) << 3)]);
#pragma unroll
                for (int mt = 0; mt < 4; mt++) {
                    acc1[mt][nt] = __builtin_amdgcn_mfma_f32_16x16x32_bf16(af[mt], b1f, acc1[mt][nt], 0, 0, 0);
                    acc2[mt][nt] = __builtin_amdgcn_mfma_f32_16x16x32_bf16(af[mt], b2f, acc2[mt][nt], 0, 0, 0);
                }
            }
        }
    }

    const u32 obase = offsets[e];
    const int rbv = qb * 4;
#pragma unroll
    for (int nt = 0; nt < 2; nt++) {
        const int n = n0 + ncol0 + nt * 16 + mm;
        const float bb1 = ldf<MODE>(fc1_b, (size_t)e * 2 * HDIM + n);
        const float bb2 = ldf<MODE>(fc1_b, (size_t)e * 2 * HDIM + HDIM + n);
#pragma unroll
        for (int mt = 0; mt < 4; mt++) {
#pragma unroll
            for (int r = 0; r < 4; r++) {
                const int gr = row0 + mrow0 + mt * 16 + rbv + r;
                if (gr < cnt) {
                    const float h1 = acc1[mt][nt][r] + bb1;
                    const float h2 = acc2[mt][nt][r] + bb2;
                    const float av = h1 / (1.f + __expf(-h1)) * h2;
                    a_packed[(size_t)(obase + (u32)gr) * HDIM + n] = f2b(av);
                }
            }
        }
    }
}

// ---------------- K4: fc2, 128x64 tile, prefetched ----------------
template<int MODE>
__global__ __launch_bounds__(256, 3) void fc2_kernel(
    const u32* __restrict__ flag,
    const u16* __restrict__ a_packed, const void* __restrict__ fc2_w, const void* __restrict__ fc2_b,
    const u32* __restrict__ counts, const u32* __restrict__ offsets,
    u16* __restrict__ y_packed)
{
    if (*flag != 0u) return;   // zero word in both paths
    const int e = blockIdx.z;
    const int cnt = (int)counts[e];
    const int row0 = blockIdx.y * 128;
    if (row0 >= cnt) return;
    const int d0 = blockIdx.x * 64;

    __shared__ u16 As[128 * 64], Bs[64 * 64];

    const int tid = threadIdx.x;
    const int lr = tid >> 2;
    const int lcc = tid & 3;
    const int lc = lcc * 16;
    const u32 obase = offsets[e];

    int ar0 = row0 + lr;       if (ar0 >= cnt) ar0 = cnt - 1;
    int ar1 = row0 + 64 + lr;  if (ar1 >= cnt) ar1 = cnt - 1;
    const size_t a_base0 = (size_t)(obase + (u32)ar0) * HDIM;
    const size_t a_base1 = (size_t)(obase + (u32)ar1) * HDIM;
    const size_t b_base  = ((size_t)e * DDIM + (size_t)(d0 + lr)) * HDIM;

    const int sw = lr & 7;
    const int c0 = lcc * 2;
    u16* as0a = &As[lr * 64 + ((c0 ^ sw) << 3)];
    u16* as0b = &As[lr * 64 + (((c0 + 1) ^ sw) << 3)];
    u16* as1a = &As[(lr + 64) * 64 + ((c0 ^ sw) << 3)];
    u16* as1b = &As[(lr + 64) * 64 + (((c0 + 1) ^ sw) << 3)];
    u16* bsa  = &Bs[lr * 64 + ((c0 ^ sw) << 3)];
    u16* bsb  = &Bs[lr * 64 + (((c0 + 1) ^ sw) << 3)];

    const int wave = tid >> 6, lane = tid & 63;
    const int mrow0 = (wave >> 1) * 64;
    const int ncol0 = (wave & 1) * 32;
    const int mm = lane & 15;
    const int qb = lane >> 4;
    const int msw = mm & 7;

    f32x4 acc[4][2];
#pragma unroll
    for (int mt = 0; mt < 4; mt++)
#pragma unroll
        for (int nt = 0; nt < 2; nt++) acc[mt][nt] = f32x4{0, 0, 0, 0};

    uint4 A0l, A0h, A1l, A1h, Bl, Bh;
    load16<0>(a_packed, a_base0 + lc, A0l, A0h);
    load16<0>(a_packed, a_base1 + lc, A1l, A1h);
    load16<MODE>(fc2_w, b_base + lc, Bl, Bh);

    for (int k0 = 0; k0 < HDIM; k0 += 64) {
        __syncthreads();
        *(uint4*)as0a = A0l; *(uint4*)as0b = A0h;
        *(uint4*)as1a = A1l; *(uint4*)as1b = A1h;
        *(uint4*)bsa  = Bl;  *(uint4*)bsb  = Bh;
        __syncthreads();
        if (k0 + 64 < HDIM) {
            load16<0>(a_packed, a_base0 + k0 + 64 + lc, A0l, A0h);
            load16<0>(a_packed, a_base1 + k0 + 64 + lc, A1l, A1h);
            load16<MODE>(fc2_w, b_base + k0 + 64 + lc, Bl, Bh);
        }
#pragma unroll
        for (int kk = 0; kk < 2; kk++) {
            const int g = kk * 4 + qb;
            bf16x8 af[4];
#pragma unroll
            for (int mt = 0; mt < 4; mt++)
                af[mt] = *(const bf16x8*)(&As[(mrow0 + mt * 16 + mm) * 64 + ((g ^ msw) << 3)]);
#pragma unroll
            for (int nt = 0; nt < 2; nt++) {
                const bf16x8 bfv = *(const bf16x8*)(&Bs[(ncol0 + nt * 16 + mm) * 64 + ((g ^ msw) << 3)]);
#pragma unroll
                for (int mt = 0; mt < 4; mt++)
                    acc[mt][nt] = __builtin_amdgcn_mfma_f32_16x16x32_bf16(af[mt], bfv, acc[mt][nt], 0, 0, 0);
            }
        }
    }

    const int rbv = qb * 4;
#pragma unroll
    for (int nt = 0; nt < 2; nt++) {
        const int n = d0 + ncol0 + nt * 16 + mm;
        const float bb = ldf<MODE>(fc2_b, (size_t)e * DDIM + n);
#pragma unroll
        for (int mt = 0; mt < 4; mt++) {
#pragma unroll
            for (int r = 0; r < 4; r++) {
                const int gr = row0 + mrow0 + mt * 16 + rbv + r;
                if (gr < cnt) {
                    y_packed[(size_t)(obase + (u32)gr) * DDIM + n] = f2b(acc[mt][nt][r] + bb);
                }
            }
        }
    }
}

// ---------------- K5: weighted combine (writes f32 output) ----------------
template<int MODE>
__global__ __launch_bounds__(256) void combine_kernel(
    const u32* __restrict__ flag,
    const u16* __restrict__ y_packed, const u32* __restrict__ offsets,
    const u32* __restrict__ tok_e, const u32* __restrict__ tok_pos,
    const float* __restrict__ tok_w, void* __restrict__ out)
{
    if (*flag != (u32)MODE) return;
    const int t = blockIdx.x;
    const u32 e0 = tok_e[t * 2] & 7u, e1 = tok_e[t * 2 + 1] & 7u;
    const u32 p0 = min(offsets[e0] + tok_pos[t * 2], (u32)(2 * NTOK - 1));
    const u32 p1 = min(offsets[e1] + tok_pos[t * 2 + 1], (u32)(2 * NTOK - 1));
    const float w0 = tok_w[t * 2], w1 = tok_w[t * 2 + 1];
    const u16* y0 = y_packed + (size_t)p0 * DDIM;
    const u16* y1 = y_packed + (size_t)p1 * DDIM;
    for (int c = threadIdx.x; c < DDIM; c += 256) {
        const float v = w0 * b2f(y0[c]) + w1 * b2f(y1[c]);
        if (MODE == 0) ((u16*)out)[(size_t)t * DDIM + c] = f2b(v);
        else           ((float*)out)[(size_t)t * DDIM + c] = v;
    }
}

extern "C" void kernel_launch(void* const* d_in, const int* in_sizes, int n_in,
                              void* d_out, int out_size, void* d_ws, size_t ws_size,
                              hipStream_t stream)
{
    const void* x     = d_in[0];
    const void* rw    = d_in[1];
    const void* rb    = d_in[2];
    const void* fc1_w = d_in[3];
    const void* fc1_b = d_in[4];
    const void* fc2_w = d_in[5];
    const void* fc2_b = d_in[6];

    char* ws = (char*)d_ws;
    size_t off = 0;
    auto take = [&](size_t bytes) -> char* {
        char* p = ws + off;
        off = (off + bytes + 255) & ~(size_t)255;
        return p;
    };
    u32* flag      = (u32*)take(8);            // [0]=dtype flag, [1]=zero word
    u32* zflag     = flag + 1;
    u32* counts    = (u32*)take(NEXP * 4);
    u32* offsets   = (u32*)take(NEXP * 4);
    u16* list      = (u16*)take((size_t)NEXP * NTOK * 2);
    u16* tok_epack = (u16*)take((size_t)NTOK * 2);
    u32* tok_e     = (u32*)take((size_t)NTOK * 2 * 4);
    u32* tok_pos   = (u32*)take((size_t)NTOK * 2 * 4);
    float* tok_w   = (float*)take((size_t)NTOK * 2 * 4);
    u16* a_packed  = (u16*)take((size_t)2 * NTOK * HDIM * 2);   // 16 MB
    u16* y_pack    = (u16*)take((size_t)2 * NTOK * DDIM * 2);   // 8 MB
    // bf16 pre-converted copies (only used if ws_size permits):
    u16* xb  = (u16*)take((size_t)NTOK * DDIM * 2);            // 4 MB
    u16* w1b = (u16*)take((size_t)NEXP * 2 * HDIM * DDIM * 2); // 16.78 MB
    u16* b1b = (u16*)take((size_t)NEXP * 2 * HDIM * 2);
    u16* w2b = (u16*)take((size_t)NEXP * DDIM * HDIM * 2);     // 8.39 MB
    u16* b2b = (u16*)take((size_t)NEXP * DDIM * 2);
    const bool use_conv = (off <= ws_size);
    (void)in_sizes; (void)n_in; (void)out_size;

    detect_kernel<<<1, 64, 0, stream>>>((const u16*)x, flag, zflag, counts);

    router_kernel<1><<<NTOK / 4, 256, 0, stream>>>(flag, x, rw, rb, tok_epack, tok_e, tok_w);

    build_lists_kernel<<<1, 512, 0, stream>>>(tok_epack, counts, offsets, list, tok_pos);

    const dim3 g1(HDIM / 64, NTOK / 128, NEXP);
    const dim3 g2(DDIM / 64, NTOK / 128, NEXP);

    if (use_conv) {
        convert_kernel<<<CONV_BLOCKS, 256, 0, stream>>>(
            (const float*)x, (const float*)fc1_w, (const float*)fc1_b,
            (const float*)fc2_w, (const float*)fc2_b, xb, w1b, b1b, w2b, b2b);
        fc1_swiglu_kernel<0><<<g1, 256, 0, stream>>>(zflag, xb, w1b, b1b, counts, offsets, list, a_packed);
        fc2_kernel<0><<<g2, 256, 0, stream>>>(zflag, a_packed, w2b, b2b, counts, offsets, y_pack);
    } else {
        fc1_swiglu_kernel<1><<<g1, 256, 0, stream>>>(zflag, x, fc1_w, fc1_b, counts, offsets, list, a_packed);
        fc2_kernel<1><<<g2, 256, 0, stream>>>(zflag, a_packed, fc2_w, fc2_b, counts, offsets, y_pack);
    }

    combine_kernel<1><<<NTOK, 256, 0, stream>>>(flag, y_pack, offsets, tok_e, tok_pos, tok_w, d_out);
}